// Round 6
// baseline (255.363 us; speedup 1.0000x reference)
//
#include <hip/hip_runtime.h>
#include <hip/hip_bf16.h>

#define B_ROWS 131072
#define H 128
#define BM 128
#define TILES 4
#define NBLK (B_ROWS / (BM * TILES))   // 256 blocks = 1/CU

typedef __bf16 bf16x8 __attribute__((ext_vector_type(8)));
typedef float f32x4 __attribute__((ext_vector_type(4)));

#define LOG2E 1.4426950408889634f

__device__ __forceinline__ float fast_sigmoid(float x) {
    return __builtin_amdgcn_rcpf(1.0f + __builtin_amdgcn_exp2f(-LOG2E * x));
}
__device__ __forceinline__ float fast_tanh(float x) {
    // tanh(x) = 1 - 2/(exp(2x)+1)
    return 1.0f - 2.0f * __builtin_amdgcn_rcpf(1.0f + __builtin_amdgcn_exp2f(2.0f * LOG2E * x));
}

struct WPtrs {
    const float* wx[4];
    const float* wh[4];
    const float* bx[4];
    const float* bh[4];
};

// Wcat[n][k]: n = gate*128 + hidden_unit, k in [0,256) = [X-k | h-k]. bsum[n] = bx+bh.
__global__ __launch_bounds__(256) void prep_weights(WPtrs p, __bf16* __restrict__ wcat,
                                                    float* __restrict__ bsum) {
    int n = blockIdx.x;      // 0..511
    int k = threadIdx.x;     // 0..255
    int g = n >> 7, r = n & 127;
    float v = (k < H) ? p.wx[g][r * H + k] : p.wh[g][r * H + (k - H)];
    wcat[n * 256 + k] = (__bf16)v;
    if (k == 0) bsum[n] = p.bx[g][r] + p.bh[g][r];
}

// 1024 thr = 16 waves: rg (2 row-groups of 64 rows) x cg (8 col-groups of 16 units).
// BM=128 amortizes the 256KB weight stream 4x better than BM=32 (R3's hidden 30us).
// (1024,1) -> 16 waves/CU min -> 128-VGPR cap; MFMA-phase liveness ~100 so no spill.
__global__ __launch_bounds__(1024, 1) void lstm_fused(
    const float* __restrict__ X, const float* __restrict__ Hp, const float* __restrict__ Cp,
    const __bf16* __restrict__ Wcat, const float* __restrict__ Bsum,
    float* __restrict__ out)
{
    __shared__ char abuf[BM * 512];          // 64 KB bf16 [X|h] tile, XOR-swizzled, single-buffered

    const int t = threadIdx.x;
    const int lane = t & 63;
    const int wv = t >> 6;                   // 0..15
    const int rg = wv >> 3;                  // 0..1 : rows rg*64..rg*64+63
    const int cg = wv & 7;                   // 0..7 : units cg*16..cg*16+15
    const int l16 = lane & 15;
    const int kg = lane >> 4;                // 0..3
    const long base = (long)blockIdx.x * (BM * TILES);
    const long c_off = (long)B_ROWS * H;

    const int j = cg * 16 + l16;             // this lane's hidden unit (all 4 gates)
    const __bf16* wbase = Wcat + (long)j * 256 + kg * 8;

    float bias[4];
#pragma unroll
    for (int g = 0; g < 4; ++g) bias[g] = Bsum[g * H + j];

    // staging map: thread t covers rows {q*32 + (t>>5)}, float4-col t&31
    const int sr = t >> 5;                   // 0..31
    const int c4 = t & 31;

    float4 sx[4], sh[4];

    // prologue: issue tile-0 X/h loads
#pragma unroll
    for (int q = 0; q < 4; ++q) {
        long row = base + q * 32 + sr;
        sx[q] = *(const float4*)(X  + row * H + c4 * 4);
        sh[q] = *(const float4*)(Hp + row * H + c4 * 4);
    }

    for (int tile = 0; tile < TILES; ++tile) {
        const long r0 = base + tile * BM;

        // ---- stage regs -> LDS (bf16, swizzled). Loads were issued last tile. ----
#pragma unroll
        for (int q = 0; q < 4; ++q) {
            int row = q * 32 + sr;
            int swz = (row & 7) << 4;
            union { __bf16 b[4]; unsigned long long u; } px, ph;
            float4 vx = sx[q], vh = sh[q];
            px.b[0] = (__bf16)vx.x; px.b[1] = (__bf16)vx.y;
            px.b[2] = (__bf16)vx.z; px.b[3] = (__bf16)vx.w;
            ph.b[0] = (__bf16)vh.x; ph.b[1] = (__bf16)vh.y;
            ph.b[2] = (__bf16)vh.z; ph.b[3] = (__bf16)vh.w;
            *(unsigned long long*)(abuf + row * 512 + ((c4 * 8) ^ swz)) = px.u;
            *(unsigned long long*)(abuf + row * 512 + ((256 + c4 * 8) ^ swz)) = ph.u;
        }
        __syncthreads();

        // ---- MFMA: K=256 in 8 chunks; B streams from L1/L2 (rg-pair shares via L1) ----
        f32x4 acc[4][4] = {};                // [gate][rt], 64 VGPR
#pragma unroll
        for (int kc = 0; kc < 8; ++kc) {
            bf16x8 b[4];
#pragma unroll
            for (int g = 0; g < 4; ++g)
                b[g] = *(const bf16x8*)(wbase + g * (128 * 256) + kc * 32);
#pragma unroll
            for (int rt = 0; rt < 4; ++rt) {
                int row = rg * 64 + rt * 16 + l16;
                int off = row * 512 + ((kc * 64 + kg * 16) ^ ((row & 7) << 4));
                bf16x8 a = *(const bf16x8*)(abuf + off);
#pragma unroll
                for (int g = 0; g < 4; ++g)
                    acc[g][rt] = __builtin_amdgcn_mfma_f32_16x16x32_bf16(a, b[g], acc[g][rt], 0, 0, 0);
            }
        }

        // ---- issue NEXT tile X/h loads now; latency hides under epilogue+barrier ----
        if (tile + 1 < TILES) {
            long rn = r0 + BM;
#pragma unroll
            for (int q = 0; q < 4; ++q) {
                long row = rn + q * 32 + sr;
                sx[q] = *(const float4*)(X  + row * H + c4 * 4);
                sh[q] = *(const float4*)(Hp + row * H + c4 * 4);
            }
        }

        // ---- epilogue: scattered cp loads (64B segments), gate math, scattered stores ----
        const float* cpb = Cp  + (r0 + rg * 64 + kg * 4) * H + j;
        float*       hb  = out + (r0 + rg * 64 + kg * 4) * H + j;
        float*       cb  = out + c_off + (r0 + rg * 64 + kg * 4) * H + j;

        float cpv[16];
#pragma unroll
        for (int rt = 0; rt < 4; ++rt)
#pragma unroll
            for (int r = 0; r < 4; ++r)
                cpv[rt * 4 + r] = cpb[(rt * 16 + r) * H];

#pragma unroll
        for (int rt = 0; rt < 4; ++rt) {
#pragma unroll
            for (int r = 0; r < 4; ++r) {
                float f  = acc[0][rt][r] + bias[0];
                float ii = acc[1][rt][r] + bias[1];
                float cl = acc[2][rt][r] + bias[2];
                float oo = acc[3][rt][r] + bias[3];
                float ft = fast_sigmoid(f);
                float it = fast_sigmoid(ii);
                float cc = fast_tanh(cl);
                float ot = fast_sigmoid(oo);
                float ct = ft * cpv[rt * 4 + r] + it * cc;
                float ht = ot * fast_tanh(ct);
                hb[(rt * 16 + r) * H] = ht;
                cb[(rt * 16 + r) * H] = ct;
            }
        }
        __syncthreads();   // abuf reads done before next tile's ds_writes
    }
}

extern "C" void kernel_launch(void* const* d_in, const int* in_sizes, int n_in,
                              void* d_out, int out_size, void* d_ws, size_t ws_size,
                              hipStream_t stream) {
    const float* X  = (const float*)d_in[0];
    const float* Hp = (const float*)d_in[1];
    const float* Cp = (const float*)d_in[2];
    WPtrs p;
    p.wx[0] = (const float*)d_in[3];  p.bx[0] = (const float*)d_in[4];
    p.wh[0] = (const float*)d_in[5];  p.bh[0] = (const float*)d_in[6];
    p.wx[1] = (const float*)d_in[7];  p.bx[1] = (const float*)d_in[8];
    p.wh[1] = (const float*)d_in[9];  p.bh[1] = (const float*)d_in[10];
    p.wx[2] = (const float*)d_in[11]; p.bx[2] = (const float*)d_in[12];
    p.wh[2] = (const float*)d_in[13]; p.bh[2] = (const float*)d_in[14];
    p.wx[3] = (const float*)d_in[15]; p.bx[3] = (const float*)d_in[16];
    p.wh[3] = (const float*)d_in[17]; p.bh[3] = (const float*)d_in[18];

    __bf16* wcat = (__bf16*)d_ws;
    float*  bsum = (float*)((char*)d_ws + 512 * 256 * 2);

    prep_weights<<<512, 256, 0, stream>>>(p, wcat, bsum);
    lstm_fused<<<NBLK, 1024, 0, stream>>>(X, Hp, Cp, wcat, bsum, (float*)d_out);
}

// Round 7
// 106.728 us; speedup vs baseline: 2.3927x; 2.3927x over previous
//
#include <hip/hip_runtime.h>
#include <hip/hip_bf16.h>

#define B_ROWS 131072
#define H 128
#define BM 32
#define TILES 8
#define NBLK (B_ROWS / (BM * TILES))   // 512 blocks -> 2 resident per CU

typedef __bf16 bf16x8 __attribute__((ext_vector_type(8)));
typedef float f32x4 __attribute__((ext_vector_type(4)));

#define LOG2E 1.4426950408889634f

__device__ __forceinline__ float fast_sigmoid(float x) {
    return __builtin_amdgcn_rcpf(1.0f + __builtin_amdgcn_exp2f(-LOG2E * x));
}
__device__ __forceinline__ float fast_tanh(float x) {
    return 1.0f - 2.0f * __builtin_amdgcn_rcpf(1.0f + __builtin_amdgcn_exp2f(2.0f * LOG2E * x));
}

struct WPtrs {
    const float* wx[4];
    const float* wh[4];
    const float* bx[4];
    const float* bh[4];
};

// Wcat[n][k]: n = gate*128 + hidden_unit, k in [0,256) = [X-k | h-k]. bsum[n] = bx+bh.
__global__ __launch_bounds__(256) void prep_weights(WPtrs p, __bf16* __restrict__ wcat,
                                                    float* __restrict__ bsum) {
    int n = blockIdx.x;      // 0..511
    int k = threadIdx.x;     // 0..255
    int g = n >> 7, r = n & 127;
    float v = (k < H) ? p.wx[g][r * H + k] : p.wh[g][r * H + (k - H)];
    wcat[n * 256 + k] = (__bf16)v;
    if (k == 0) bsum[n] = p.bx[g][r] + p.bh[g][r];
}

// 512 thr + (512,2): empirically VGPR cap 128, no spill (R3). 1024-thr / (_,4) -> 64-cap spill. BANNED.
// LDS = 16.4 KB only (A-tile). Epilogue is transpose-free: gates are lane-local in the MFMA
// C/D layout; scattered 64B-grain cp loads + hc stores are assembled into full lines by L2.
__global__ __launch_bounds__(512, 2) void lstm_fused(
    const float* __restrict__ X, const float* __restrict__ Hp, const float* __restrict__ Cp,
    const __bf16* __restrict__ Wcat, const float* __restrict__ Bsum,
    float* __restrict__ out)
{
    __shared__ char alds[BM * 512];          // 16.4 KB bf16 [X|h] tile, XOR-swizzled

    const int t = threadIdx.x;
    const int lane = t & 63;
    const int cg = t >> 6;                   // wave 0..7 -> hidden cols [cg*16, cg*16+16)
    const int l16 = lane & 15;
    const int kg = lane >> 4;                // 0..3
    const long base = (long)blockIdx.x * (BM * TILES);
    const long c_off = (long)B_ROWS * H;

    const int j = cg * 16 + l16;             // this lane's hidden unit (all 4 gates)
    const __bf16* wbase = Wcat + (long)j * 256 + kg * 8;

    float bias[4];
#pragma unroll
    for (int g = 0; g < 4; ++g) bias[g] = Bsum[g * H + j];

    // coalesced staging map: thread t covers rows r_q0/r_q1, float4-col c4
    const int r_q0 = t >> 5;                 // 0..15
    const int r_q1 = 16 + (t >> 5);          // 16..31
    const int c4 = t & 31;

    float4 sx[2], sh[2];

    // prologue: issue tile-0 X/h loads
    sx[0] = *(const float4*)(X  + (base + r_q0) * H + c4 * 4);
    sh[0] = *(const float4*)(Hp + (base + r_q0) * H + c4 * 4);
    sx[1] = *(const float4*)(X  + (base + r_q1) * H + c4 * 4);
    sh[1] = *(const float4*)(Hp + (base + r_q1) * H + c4 * 4);

    for (int tile = 0; tile < TILES; ++tile) {
        const long r0 = base + tile * BM;

        // ---- Phase A: staged regs -> LDS (bf16, swizzled) ----
#pragma unroll
        for (int q = 0; q < 2; ++q) {
            int row = q ? r_q1 : r_q0;
            int swz = (row & 7) << 4;
            union { __bf16 b[4]; unsigned long long u; } px, ph;
            float4 vx = sx[q], vh = sh[q];
            px.b[0] = (__bf16)vx.x; px.b[1] = (__bf16)vx.y;
            px.b[2] = (__bf16)vx.z; px.b[3] = (__bf16)vx.w;
            ph.b[0] = (__bf16)vh.x; ph.b[1] = (__bf16)vh.y;
            ph.b[2] = (__bf16)vh.z; ph.b[3] = (__bf16)vh.w;
            *(unsigned long long*)(alds + row * 512 + ((c4 * 8) ^ swz)) = px.u;
            *(unsigned long long*)(alds + row * 512 + ((256 + c4 * 8) ^ swz)) = ph.u;
        }
        __syncthreads();

        // ---- issue this tile's cp loads (scattered 64B-grain; latency hides under MFMA) ----
        float cpv[8];
#pragma unroll
        for (int rt = 0; rt < 2; ++rt)
#pragma unroll
            for (int r = 0; r < 4; ++r)
                cpv[rt * 4 + r] = Cp[(r0 + rt * 16 + kg * 4 + r) * H + j];

        // ---- issue next tile's X/h loads ----
        if (tile + 1 < TILES) {
            long rn = r0 + BM;
            sx[0] = *(const float4*)(X  + (rn + r_q0) * H + c4 * 4);
            sh[0] = *(const float4*)(Hp + (rn + r_q0) * H + c4 * 4);
            sx[1] = *(const float4*)(X  + (rn + r_q1) * H + c4 * 4);
            sh[1] = *(const float4*)(Hp + (rn + r_q1) * H + c4 * 4);
        }

        // ---- MFMA: 8 K-chunks x 4 gates x 2 row-tiles; B streams from L1/L2 ----
        f32x4 acc[4][2] = {};
#pragma unroll
        for (int kc = 0; kc < 8; ++kc) {
            bf16x8 a[2];
#pragma unroll
            for (int rt = 0; rt < 2; ++rt) {
                int row = rt * 16 + l16;
                int off = row * 512 + ((kc * 64 + kg * 16) ^ ((row & 7) << 4));
                a[rt] = *(const bf16x8*)(alds + off);
            }
#pragma unroll
            for (int g = 0; g < 4; ++g) {
                bf16x8 b = *(const bf16x8*)(wbase + g * (128 * 256) + kc * 32);
                acc[g][0] = __builtin_amdgcn_mfma_f32_16x16x32_bf16(a[0], b, acc[g][0], 0, 0, 0);
                acc[g][1] = __builtin_amdgcn_mfma_f32_16x16x32_bf16(a[1], b, acc[g][1], 0, 0, 0);
            }
        }
        __syncthreads();   // alds fully consumed; next tile may restage

        // ---- epilogue in scatter layout: gates lane-local, fast activations ----
#pragma unroll
        for (int rt = 0; rt < 2; ++rt) {
#pragma unroll
            for (int r = 0; r < 4; ++r) {
                long row = r0 + rt * 16 + kg * 4 + r;   // C/D layout: row=(lane>>4)*4+reg
                float f  = acc[0][rt][r] + bias[0];
                float ii = acc[1][rt][r] + bias[1];
                float cl = acc[2][rt][r] + bias[2];
                float oo = acc[3][rt][r] + bias[3];
                float ft = fast_sigmoid(f);
                float it = fast_sigmoid(ii);
                float cc = fast_tanh(cl);
                float ot = fast_sigmoid(oo);
                float ct = ft * cpv[rt * 4 + r] + it * cc;
                float ht = ot * fast_tanh(ct);
                out[row * H + j] = ht;
                out[c_off + row * H + j] = ct;
            }
        }
    }
}

extern "C" void kernel_launch(void* const* d_in, const int* in_sizes, int n_in,
                              void* d_out, int out_size, void* d_ws, size_t ws_size,
                              hipStream_t stream) {
    const float* X  = (const float*)d_in[0];
    const float* Hp = (const float*)d_in[1];
    const float* Cp = (const float*)d_in[2];
    WPtrs p;
    p.wx[0] = (const float*)d_in[3];  p.bx[0] = (const float*)d_in[4];
    p.wh[0] = (const float*)d_in[5];  p.bh[0] = (const float*)d_in[6];
    p.wx[1] = (const float*)d_in[7];  p.bx[1] = (const float*)d_in[8];
    p.wh[1] = (const float*)d_in[9];  p.bh[1] = (const float*)d_in[10];
    p.wx[2] = (const float*)d_in[11]; p.bx[2] = (const float*)d_in[12];
    p.wh[2] = (const float*)d_in[13]; p.bh[2] = (const float*)d_in[14];
    p.wx[3] = (const float*)d_in[15]; p.bx[3] = (const float*)d_in[16];
    p.wh[3] = (const float*)d_in[17]; p.bh[3] = (const float*)d_in[18];

    __bf16* wcat = (__bf16*)d_ws;
    float*  bsum = (float*)((char*)d_ws + 512 * 256 * 2);

    prep_weights<<<512, 256, 0, stream>>>(p, wcat, bsum);
    lstm_fused<<<NBLK, 512, 0, stream>>>(X, Hp, Cp, wcat, bsum, (float*)d_out);
}